// Round 16
// baseline (162.796 us; speedup 1.0000x reference)
//
#include <hip/hip_runtime.h>

// ---------------------------------------------------------------------------
// AttentionFlow: linearized per-node-table formulation.
//   hc   = tanh(hidden_con @ W_h + b_h)                      (80000 x 64)
//   hu   = tanh(hidden_uncon @ W_hlg + b_hlg)                (50000 x 64)
//   Ahc  = hc @ [Wl0 | Wl1_top | Wr0 | Wr1_top]              (80001 x 256) bf16
//   Ahu  = hu @ [Wl0 | Wl1_top | Wr0 | Wr1_top] + [bl0|0|br0|0] (50000 x 256) bf16
// Tables PAIR-PACKED as u32 rows of 128: u32[x] = (l0_x lo16, l1_x hi16),
// u32[64+x] = (r0_x, r1_x). Ahc row M_MEM is all-zero (unmapped-node sink).
// per edge: l0/l1/r0/r1 tanh-dots -> logit -> exp -> segment-sum -> scatter.
//
// Structure = round-15 (139us) with stage1 LDS staging DELETED: each lane
// reads its own X row directly from global (tile fits L1: wave0 warms it,
// waves 1-3 hit). Zero stage1 barriers; x waits on vmcnt, W s_loads own
// lgkmcnt exclusively -> the r3-r14 mixed-counter drain is gone.
// r13 lesson: W must stay SMEM (readfirstlane); per-lane W = 216us disaster.
// r12 lesson: occupancy push thrashed L2; stay (256,6).
// r15: Bresenham hc/hu interleave + setprio kept.
// k_edge: 16 lanes/edge (r6: wave/edge uniform-op overhead; r7: thread/edge
//   2.8x fetch amplification; 16-lane groups = contiguous 256B + amortize).
// Fragment layouts (verified on-device r5-r8):
//   A: lane holds A[m=lane&15][k=8*(lane>>4)+i]; B: B[k=8*(lane>>4)+i][n=lane&15]
//   D: lane holds D[m=(lane>>4)*4+r][n=lane&15]
// ---------------------------------------------------------------------------

typedef __attribute__((ext_vector_type(8))) short s16x8;
typedef __attribute__((ext_vector_type(4))) float f32x4;
typedef __attribute__((ext_vector_type(8))) unsigned short u16x8;

__device__ __forceinline__ float fast_tanh(float x) {
    float e = __expf(2.0f * x);
    return 1.0f - 2.0f * __builtin_amdgcn_rcpf(e + 1.0f);
}

__device__ __forceinline__ unsigned short bf16r(float f) {   // round-to-nearest-even
    unsigned int u = __float_as_uint(f);
    u = (u + 0x7fffu + ((u >> 16) & 1u)) >> 16;
    return (unsigned short)u;
}
__device__ __forceinline__ float bf16f(unsigned short h) {
    return __uint_as_float(((unsigned int)h) << 16);
}
__device__ __forceinline__ float blo(unsigned int u) {       // low bf16 of pair
    return __uint_as_float(u << 16);
}
__device__ __forceinline__ float bhi(unsigned int u) {       // high bf16 of pair
    return __uint_as_float(u & 0xffff0000u);
}

__global__ void k_scatter_inv(const int* __restrict__ new_idx, int* __restrict__ inv, int M) {
    int i = blockIdx.x * blockDim.x + threadIdx.x;
    if (i < M) inv[new_idx[i]] = i;
}

// pack concat-W (64 x 256) into MFMA B-fragment order, hi+lo bf16 planes.
__global__ void k_pack(const float* __restrict__ Wl0, const float* __restrict__ Wl1,
                       const float* __restrict__ Wr0, const float* __restrict__ Wr1,
                       unsigned short* __restrict__ Bp) {
    int tid = blockIdx.x * blockDim.x + threadIdx.x;
    if (tid >= 2048) return;
    int lane = tid & 63;
    int ks = (tid >> 6) & 1;
    int g = tid >> 7;                       // 0..15 col-group
    int col = g * 16 + (lane & 15);         // 0..255 in concat table
    int kb = ks * 32 + (lane >> 4) * 8;
    const float* W = (col < 64) ? Wl0 : (col < 128) ? Wl1 : (col < 192) ? Wr0 : Wr1;
    int c = col & 63;
    #pragma unroll
    for (int i = 0; i < 8; ++i) {
        float w = W[(kb + i) * 64 + c];
        unsigned short hi = bf16r(w);
        unsigned short lo = bf16r(w - bf16f(hi));
        Bp[(size_t)tid * 8 + i] = hi;
        Bp[16384 + (size_t)tid * 8 + i] = lo;
    }
}

// 32 blocks x 64 threads: q-side tiny precompute
__global__ void k_q(const float* __restrict__ qhe, const float* __restrict__ qre,
                    const float* __restrict__ W_hlg, const float* __restrict__ b_hlg,
                    const float* __restrict__ W_rlg, const float* __restrict__ b_rlg,
                    const float* __restrict__ Wl1, const float* __restrict__ bl1,
                    const float* __restrict__ Wr1, const float* __restrict__ br1,
                    float* __restrict__ ql1b, float* __restrict__ qr1b) {
    __shared__ float qv_s[64];
    int b = blockIdx.x, d = threadIdx.x;
    float ah = 0.f, ar = 0.f;
    for (int k = 0; k < 256; ++k) {
        ah += qhe[b * 256 + k] * W_hlg[k * 64 + d];
        ar += qre[b * 256 + k] * W_rlg[k * 64 + d];
    }
    qv_s[d] = fast_tanh(ah + b_hlg[d]) + fast_tanh(ar + b_rlg[d]);
    __syncthreads();
    float a1 = 0.f, a2 = 0.f;
    for (int k = 0; k < 64; ++k) {
        float v = qv_s[k];
        a1 += v * Wl1[(64 + k) * 64 + d];
        a2 += v * Wr1[(64 + k) * 64 + d];
    }
    ql1b[b * 64 + d] = a1 + bl1[d];
    qr1b[b * 64 + d] = a2 + br1[d];
}

// stage1 batch: 4 f32x4 of the lane's OWN row direct from global (vmcnt),
// W via wave-uniform s_load (lgkmcnt). Counters independent -> no mixing drain.
__device__ __forceinline__ void s1_batch_g(const float* __restrict__ xg, bool rok,
                                           int koff,
                                           const float* __restrict__ Wbase, int wu,
                                           float acc1[16]) {
    f32x4 xrow[4];
    #pragma unroll
    for (int j = 0; j < 4; ++j) {
        xrow[j] = (f32x4){0.f, 0.f, 0.f, 0.f};
        if (rok) xrow[j] = *reinterpret_cast<const f32x4*>(xg + koff + j * 4);
    }
    #pragma unroll
    for (int k4 = 0; k4 < 4; ++k4) {
        #pragma unroll
        for (int kk = 0; kk < 4; ++kk) {
            float xk = xrow[k4][kk];
            const float* wrow = Wbase + (koff + k4 * 4 + kk) * 64 + wu * 16;  // s_load
            #pragma unroll
            for (int c = 0; c < 16; ++c) acc1[c] = __builtin_fmaf(xk, wrow[c], acc1[c]);
        }
    }
}

// fused table builder; hc/hu blocks Bresenham-interleaved over blockIdx
__global__ __launch_bounds__(256, 6) void k_tab(
        const float* __restrict__ Xc, const float* __restrict__ Xu,
        const float* __restrict__ W_h, const float* __restrict__ b_h,
        const float* __restrict__ W_hlg, const float* __restrict__ b_hlg,
        const float* __restrict__ bl0, const float* __restrict__ br0,
        const unsigned short* __restrict__ Bp,
        unsigned short* __restrict__ Ahc, unsigned short* __restrict__ Ahu,
        int M, int N, int HUB) {
    __shared__ unsigned short hhi[64 * 68];        // h bf16
    __shared__ unsigned short dstage[16 * 264];    // D staging (16 rows x 256 + pad)

    const int t = threadIdx.x;
    const int wu = __builtin_amdgcn_readfirstlane(t >> 6);
    const int lane = t & 63;

    // Bresenham interleave: exactly HUB hu-blocks spread uniformly over TB
    const int bid = (int)blockIdx.x;
    const int TB = (int)gridDim.x;
    const long hb = ((long)bid * HUB) / TB;              // hu-count before bid
    const bool hc = (((long)(bid + 1) * HUB) / TB) == hb;
    const int idx = hc ? (bid - (int)hb) : (int)hb;

    float acc1[16];
    #pragma unroll
    for (int c = 0; c < 16; ++c) acc1[c] = 0.f;

    int base, rows;
    const float* bias;
    unsigned short* table;

    if (hc) {
        base = idx * 64;
        rows = (M - base < 64) ? (M - base) : 64;
        bias = b_h;
        table = Ahc;
        const float* xg = Xc + (size_t)(base + lane) * 64;
        const bool rok = lane < rows;
        __builtin_amdgcn_s_setprio(1);
        #pragma unroll 1
        for (int b4 = 0; b4 < 4; ++b4)
            s1_batch_g(xg, rok, b4 * 16, W_h, wu, acc1);
        __builtin_amdgcn_s_setprio(0);
    } else {
        base = idx * 64;
        rows = (N - base < 64) ? (N - base) : 64;
        bias = b_hlg;
        table = Ahu;
        const float* xg = Xu + (size_t)(base + lane) * 256;
        const bool rok = lane < rows;
        __builtin_amdgcn_s_setprio(1);
        #pragma unroll 1
        for (int kc = 0; kc < 4; ++kc) {
            const float* Wb = W_hlg + (size_t)kc * 64 * 64;
            #pragma unroll 1
            for (int b4 = 0; b4 < 4; ++b4)
                s1_batch_g(xg + kc * 64, rok, b4 * 16, Wb, wu, acc1);
        }
        __builtin_amdgcn_s_setprio(0);
    }

    // tanh -> bf16 (single plane) into LDS; no pre-barrier needed (no LDS use before)
    {
        unsigned short hi[16];
        #pragma unroll
        for (int c = 0; c < 16; ++c)
            hi[c] = bf16r(fast_tanh(acc1[c] + bias[wu * 16 + c]));
        int o = lane * 68 + wu * 16;
        #pragma unroll
        for (int c = 0; c < 16; ++c) hhi[o + c] = hi[c];
    }
    __syncthreads();

    // stage2 MFMA: wave wu owns col-groups g = 4wu..4wu+3; K=64 (2 steps) x {Whi,Wlo}
    const s16x8* Bph = reinterpret_cast<const s16x8*>(Bp);
    const s16x8* Bpl = reinterpret_cast<const s16x8*>(Bp + 16384);
    const int l15 = lane & 15, l4 = lane >> 4;
    for (int rt = 0; rt < 4; ++rt) {
        int arow = (rt * 16 + l15) * 68 + l4 * 8;
        s16x8 a0v = *reinterpret_cast<const s16x8*>(&hhi[arow]);
        s16x8 a1v = *reinterpret_cast<const s16x8*>(&hhi[arow + 32]);
        #pragma unroll
        for (int ct = 0; ct < 4; ++ct) {
            int g = wu * 4 + ct;
            s16x8 bh0 = Bph[(g * 2 + 0) * 64 + lane];
            s16x8 bh1 = Bph[(g * 2 + 1) * 64 + lane];
            s16x8 bl0v = Bpl[(g * 2 + 0) * 64 + lane];
            s16x8 bl1v = Bpl[(g * 2 + 1) * 64 + lane];
            f32x4 acc = {0.f, 0.f, 0.f, 0.f};
            acc = __builtin_amdgcn_mfma_f32_16x16x32_bf16(a0v, bh0, acc, 0, 0, 0);
            acc = __builtin_amdgcn_mfma_f32_16x16x32_bf16(a1v, bh1, acc, 0, 0, 0);
            acc = __builtin_amdgcn_mfma_f32_16x16x32_bf16(a0v, bl0v, acc, 0, 0, 0);
            acc = __builtin_amdgcn_mfma_f32_16x16x32_bf16(a1v, bl1v, acc, 0, 0, 0);
            // fold edge-side biases into the hu table: l0 cols get bl0, r0 cols br0
            float badd = 0.f;
            if (!hc) {
                if (g < 4) badd = bl0[g * 16 + l15];
                else if (g >= 8 && g < 12) badd = br0[(g - 8) * 16 + l15];
            }
            // pair-packed column position: u16 index within 256-u16 row
            int side = g >> 3, which = (g >> 2) & 1;
            int x = (g & 3) * 16 + l15;
            int pos = side * 128 + x * 2 + which;
            #pragma unroll
            for (int r = 0; r < 4; ++r)
                dstage[(l4 * 4 + r) * 264 + pos] = bf16r(acc[r] + badd);
        }
        __syncthreads();
        // coalesced flush: 16 rows x 256 u16; 256 thr x 2 x u16x8
        #pragma unroll
        for (int it = 0; it < 2; ++it) {
            int f = (it * 256 + t) * 8;
            int row = f >> 8, off = f & 255;
            u16x8 v = *reinterpret_cast<const u16x8*>(&dstage[row * 264 + off]);
            int grow = rt * 16 + row;
            if (grow < rows)
                *reinterpret_cast<u16x8*>(&table[(size_t)(base + grow) * 256 + off]) = v;
        }
        __syncthreads();
    }
}

// 16 lanes per edge: contiguous 256B half-row reads, 4 tanh-pairs/lane, 4-level reduce.
// Folds ey*natt into trans and emits int2{outidx,seg} aux for a lean k_final.
__global__ void k_edge(const int* __restrict__ se, const int* __restrict__ inv,
                       const unsigned int* __restrict__ Ahc, const unsigned int* __restrict__ Ahu,
                       const float* __restrict__ ql1b, const float* __restrict__ qr1b,
                       const float* __restrict__ ey, const float* __restrict__ natt,
                       float* __restrict__ trans, float* __restrict__ psum,
                       int2* __restrict__ aux, int E, int N, int ZROW) {
    int tid = blockIdx.x * blockDim.x + threadIdx.x;
    int e = tid >> 4;
    int sl = tid & 15;
    if (e >= E) return;
    const int4* sr = reinterpret_cast<const int4*>(se + (size_t)e * 8);
    int4 ra = sr[0], rb = sr[1];
    int eg = ra.x, vi = ra.y, vj = ra.z, seg = rb.x, e2vi = rb.z, e2vj = rb.w;
    int ii = inv[e2vi]; ii = (ii < 0) ? ZROW : ii;
    int ij = inv[e2vj]; ij = (ij < 0) ? ZROW : ij;
    uint4 a  = *reinterpret_cast<const uint4*>(Ahc + (size_t)ii * 128 + sl * 4);
    uint4 b  = *reinterpret_cast<const uint4*>(Ahu + (size_t)vi * 128 + sl * 4);
    uint4 c  = *reinterpret_cast<const uint4*>(Ahc + (size_t)ij * 128 + 64 + sl * 4);
    uint4 d4 = *reinterpret_cast<const uint4*>(Ahu + (size_t)vj * 128 + 64 + sl * 4);
    float4 q1 = *reinterpret_cast<const float4*>(ql1b + eg * 64 + sl * 4);
    float4 q2 = *reinterpret_cast<const float4*>(qr1b + eg * 64 + sl * 4);
    float acc = 0.f;
    #pragma unroll
    for (int j = 0; j < 4; ++j) {
        unsigned int av = (&a.x)[j], bv = (&b.x)[j];
        unsigned int cv = (&c.x)[j], dv = (&d4.x)[j];
        float l0 = fast_tanh(blo(av) + blo(bv));                 // bl0 folded in Ahu
        float l1 = fast_tanh(bhi(av) + bhi(bv) + (&q1.x)[j]);
        float r0 = fast_tanh(blo(cv) + blo(dv));                 // br0 folded in Ahu
        float r1 = fast_tanh(bhi(cv) + bhi(dv) + (&q2.x)[j]);
        acc = __builtin_fmaf(l0, r0, acc);
        acc = __builtin_fmaf(l1, r1, acc);
    }
    #pragma unroll
    for (int off = 8; off; off >>= 1) acc += __shfl_xor(acc, off);
    if (sl == 0) {
        float ex = __expf(acc);          // |logit| small & inputs fixed: no max pass
        trans[e] = ex * ey[e] * natt[(size_t)eg * N + vi];
        aux[e] = make_int2(eg * N + vj, seg);
        atomicAdd(&psum[seg], ex);
    }
}

__global__ void k_final(const int2* __restrict__ aux, const float* __restrict__ trans,
                        const float* __restrict__ psum, float* __restrict__ out, int E) {
    int e = blockIdx.x * blockDim.x + threadIdx.x;
    if (e >= E) return;
    int2 a = aux[e];
    float t = trans[e] * __builtin_amdgcn_rcpf(psum[a.y]);
    atomicAdd(&out[a.x], t);
}

extern "C" void kernel_launch(void* const* d_in, const int* in_sizes, int n_in,
                              void* d_out, int out_size, void* d_ws, size_t ws_size,
                              hipStream_t stream) {
    const float* natt  = (const float*)d_in[0];
    const float* ey    = (const float*)d_in[1];
    const float* h_unc = (const float*)d_in[2];
    const float* h_con = (const float*)d_in[3];
    const float* qhe   = (const float*)d_in[4];
    const float* qre   = (const float*)d_in[5];
    const float* W_h   = (const float*)d_in[6];
    const float* b_h   = (const float*)d_in[7];
    const float* W_hlg = (const float*)d_in[8];
    const float* b_hlg = (const float*)d_in[9];
    const float* W_rlg = (const float*)d_in[10];
    const float* b_rlg = (const float*)d_in[11];
    const float* Wl0   = (const float*)d_in[12];
    const float* bl0   = (const float*)d_in[13];
    const float* Wr0   = (const float*)d_in[14];
    const float* br0   = (const float*)d_in[15];
    const float* Wl1   = (const float*)d_in[16];
    const float* bl1   = (const float*)d_in[17];
    const float* Wr1   = (const float*)d_in[18];
    const float* br1   = (const float*)d_in[19];
    const int* se      = (const int*)d_in[20];
    const int* new_idx = (const int*)d_in[21];

    const int B     = 32;
    const int N     = in_sizes[0] / B;    // 50000
    const int E     = in_sizes[20] / 8;   // 200000
    const int M_MEM = in_sizes[21];       // 80000
    const int M_ALL = 100000;
    const int NSEG  = 80000;

    char* ws = (char*)d_ws;
    size_t off = 0;
    unsigned short* Ahc = (unsigned short*)(ws + off);  off += (size_t)(M_MEM + 1) * 256 * 2;
    unsigned short* Ahu = (unsigned short*)(ws + off);  off += (size_t)N * 256 * 2;
    int* inv = (int*)(ws + off);            off += (size_t)M_ALL * 4;
    float* trans = (float*)(ws + off);      off += (size_t)E * 4;
    float* psum = (float*)(ws + off);       off += (size_t)NSEG * 4;
    int2* aux = (int2*)(ws + off);          off += (size_t)E * 8;
    float* ql1b = (float*)(ws + off);       off += (size_t)B * 64 * 4;
    float* qr1b = (float*)(ws + off);       off += (size_t)B * 64 * 4;
    unsigned short* Bpack = (unsigned short*)(ws + off); off += (size_t)2 * 16384 * 2;

    hipMemsetAsync(d_out, 0, (size_t)out_size * 4, stream);
    hipMemsetAsync(inv, 0xFF, (size_t)M_ALL * 4, stream);               // -1
    hipMemsetAsync(psum, 0, (size_t)NSEG * 4, stream);
    hipMemsetAsync(Ahc + (size_t)M_MEM * 256, 0, 256 * 2, stream);      // zero sink row

    const int HCB = (M_MEM + 63) / 64;          // 1250
    const int HUB = (N + 63) / 64;              // 782

    k_scatter_inv<<<(M_MEM + 255) / 256, 256, 0, stream>>>(new_idx, inv, M_MEM);
    k_pack<<<8, 256, 0, stream>>>(Wl0, Wl1, Wr0, Wr1, Bpack);
    k_q<<<B, 64, 0, stream>>>(qhe, qre, W_hlg, b_hlg, W_rlg, b_rlg,
                              Wl1, bl1, Wr1, br1, ql1b, qr1b);
    k_tab<<<HCB + HUB, 256, 0, stream>>>(h_con, h_unc, W_h, b_h, W_hlg, b_hlg,
                                         bl0, br0, Bpack, Ahc, Ahu, M_MEM, N, HUB);
    k_edge<<<((size_t)E * 16 + 255) / 256, 256, 0, stream>>>(se, inv, (const unsigned int*)Ahc,
                                                (const unsigned int*)Ahu, ql1b, qr1b,
                                                ey, natt, trans, psum, aux, E, N, M_MEM);
    k_final<<<(E + 255) / 256, 256, 0, stream>>>(aux, trans, psum, (float*)d_out, E);
}

// Round 17
// 136.322 us; speedup vs baseline: 1.1942x; 1.1942x over previous
//
#include <hip/hip_runtime.h>

// ---------------------------------------------------------------------------
// AttentionFlow: linearized per-node-table formulation.
//   hc   = tanh(hidden_con @ W_h + b_h)                      (80000 x 64)
//   hu   = tanh(hidden_uncon @ W_hlg + b_hlg)                (50000 x 64)
//   Ahc  = hc @ [Wl0 | Wl1_top | Wr0 | Wr1_top]              (80001 x 256) bf16
//   Ahu  = hu @ [Wl0 | Wl1_top | Wr0 | Wr1_top] + [bl0|0|br0|0] (50000 x 256) bf16
// Tables PAIR-PACKED as u32 rows of 128: u32[x] = (l0_x lo16, l1_x hi16),
// u32[64+x] = (r0_x, r1_x). Ahc row M_MEM is all-zero (unmapped-node sink).
// per edge: l0/l1/r0/r1 tanh-dots -> logit -> exp -> segment-sum -> scatter.
//
// Structure = round-15 optimum (139.2us) + fused prolog (scatter_inv + pack
// + q in ONE dispatch; cuts 2 launch/drain gaps).
// r16 lesson: per-lane own-row global X reads = 64-line address divergence
// per wave-load (112us); LDS staging IS the coalescing device. Kept.
// r13 lesson: W must stay SMEM (readfirstlane); per-lane VMEM W = 216us.
// r12 lesson: occupancy push thrashed L2; stay (256,6).
// r14: x batched into VGPRs (4x fewer lgkm drains); r15: Bresenham hc/hu
// interleave + setprio.
// k_edge: 16 lanes/edge (r6: wave/edge uniform-op overhead; r7: thread/edge
//   2.8x fetch amplification; 16-lane groups = contiguous 256B + amortize).
// Fragment layouts (verified on-device r5-r8):
//   A: lane holds A[m=lane&15][k=8*(lane>>4)+i]; B: B[k=8*(lane>>4)+i][n=lane&15]
//   D: lane holds D[m=(lane>>4)*4+r][n=lane&15]
// ---------------------------------------------------------------------------

typedef __attribute__((ext_vector_type(8))) short s16x8;
typedef __attribute__((ext_vector_type(4))) float f32x4;
typedef __attribute__((ext_vector_type(8))) unsigned short u16x8;

__device__ __forceinline__ float fast_tanh(float x) {
    float e = __expf(2.0f * x);
    return 1.0f - 2.0f * __builtin_amdgcn_rcpf(e + 1.0f);
}

__device__ __forceinline__ unsigned short bf16r(float f) {   // round-to-nearest-even
    unsigned int u = __float_as_uint(f);
    u = (u + 0x7fffu + ((u >> 16) & 1u)) >> 16;
    return (unsigned short)u;
}
__device__ __forceinline__ float bf16f(unsigned short h) {
    return __uint_as_float(((unsigned int)h) << 16);
}
__device__ __forceinline__ float blo(unsigned int u) {       // low bf16 of pair
    return __uint_as_float(u << 16);
}
__device__ __forceinline__ float bhi(unsigned int u) {       // high bf16 of pair
    return __uint_as_float(u & 0xffff0000u);
}

// swizzled LDS address for fp32 X staging: row stride 64 floats, 16B-chunk XOR
__device__ __forceinline__ int saddr(int row, int chunk) {
    return (row << 6) + ((chunk ^ (row & 7)) << 2);
}

// Fused prolog: blocks [0,SCB) scatter_inv; [SCB,SCB+8) pack; [SCB+8,SCB+16) q.
__global__ void k_prolog(const int* __restrict__ new_idx, int* __restrict__ inv, int M,
                         const float* __restrict__ Wl0, const float* __restrict__ Wl1,
                         const float* __restrict__ Wr0, const float* __restrict__ Wr1,
                         unsigned short* __restrict__ Bp,
                         const float* __restrict__ qhe, const float* __restrict__ qre,
                         const float* __restrict__ W_hlg, const float* __restrict__ b_hlg,
                         const float* __restrict__ W_rlg, const float* __restrict__ b_rlg,
                         const float* __restrict__ bl1, const float* __restrict__ br1,
                         float* __restrict__ ql1b, float* __restrict__ qr1b,
                         int SCB) {
    const int bid = (int)blockIdx.x;
    const int t = threadIdx.x;
    if (bid < SCB) {
        int i = bid * 256 + t;
        if (i < M) inv[new_idx[i]] = i;
    } else if (bid < SCB + 8) {
        // pack concat-W (64 x 256) into MFMA B-fragment order, hi+lo bf16 planes.
        int tid = (bid - SCB) * 256 + t;
        int lane = tid & 63;
        int ks = (tid >> 6) & 1;
        int g = tid >> 7;                       // 0..15 col-group
        int col = g * 16 + (lane & 15);         // 0..255 in concat table
        int kb = ks * 32 + (lane >> 4) * 8;
        const float* W = (col < 64) ? Wl0 : (col < 128) ? Wl1 : (col < 192) ? Wr0 : Wr1;
        int c = col & 63;
        #pragma unroll
        for (int i = 0; i < 8; ++i) {
            float w = W[(kb + i) * 64 + c];
            unsigned short hi = bf16r(w);
            unsigned short lo = bf16r(w - bf16f(hi));
            Bp[(size_t)tid * 8 + i] = hi;
            Bp[16384 + (size_t)tid * 8 + i] = lo;
        }
    } else {
        // q-side precompute: 4 batch-rows per block
        __shared__ float qv_s[4][64];
        int sub = t >> 6, d = t & 63;
        int b = (bid - SCB - 8) * 4 + sub;      // 0..31
        float ah = 0.f, ar = 0.f;
        for (int k = 0; k < 256; ++k) {
            ah += qhe[b * 256 + k] * W_hlg[k * 64 + d];
            ar += qre[b * 256 + k] * W_rlg[k * 64 + d];
        }
        qv_s[sub][d] = fast_tanh(ah + b_hlg[d]) + fast_tanh(ar + b_rlg[d]);
        __syncthreads();
        float a1 = 0.f, a2 = 0.f;
        for (int k = 0; k < 64; ++k) {
            float v = qv_s[sub][k];
            a1 += v * Wl1[(64 + k) * 64 + d];
            a2 += v * Wr1[(64 + k) * 64 + d];
        }
        ql1b[b * 64 + d] = a1 + bl1[d];
        qr1b[b * 64 + d] = a2 + br1[d];
    }
}

// stage1 inner: one batch of 4 k4-groups; x in VGPRs (static idx), W via SMEM
__device__ __forceinline__ void s1_batch(const float* __restrict__ s, int lane, int b4,
                                         const float* __restrict__ Wbase, int wu,
                                         float acc1[16]) {
    f32x4 xrow[4];
    #pragma unroll
    for (int j = 0; j < 4; ++j)
        xrow[j] = *reinterpret_cast<const f32x4*>(&s[saddr(lane, b4 * 4 + j)]);
    #pragma unroll
    for (int k4 = 0; k4 < 4; ++k4) {
        #pragma unroll
        for (int kk = 0; kk < 4; ++kk) {
            float xk = xrow[k4][kk];
            const float* wrow = Wbase + ((b4 * 4 + k4) * 4 + kk) * 64 + wu * 16;  // wave-uniform -> s_load
            #pragma unroll
            for (int c = 0; c < 16; ++c) acc1[c] = __builtin_fmaf(xk, wrow[c], acc1[c]);
        }
    }
}

// fused table builder; hc/hu blocks Bresenham-interleaved over blockIdx
__global__ __launch_bounds__(256, 6) void k_tab(
        const float* __restrict__ Xc, const float* __restrict__ Xu,
        const float* __restrict__ W_h, const float* __restrict__ b_h,
        const float* __restrict__ W_hlg, const float* __restrict__ b_hlg,
        const float* __restrict__ bl0, const float* __restrict__ br0,
        const unsigned short* __restrict__ Bp,
        unsigned short* __restrict__ Ahc, unsigned short* __restrict__ Ahu,
        int M, int N, int HUB) {
    __shared__ float s[64 * 64];                   // X fp32 staging; reused as h bf16 [64][68]
    __shared__ unsigned short dstage[16 * 264];    // D staging (16 rows x 256 + pad)
    unsigned short* hhi = reinterpret_cast<unsigned short*>(s);

    const int t = threadIdx.x;
    const int wu = __builtin_amdgcn_readfirstlane(t >> 6);
    const int lane = t & 63;

    // Bresenham interleave: exactly HUB hu-blocks spread uniformly over TB
    const int bid = (int)blockIdx.x;
    const int TB = (int)gridDim.x;
    const long hb = ((long)bid * HUB) / TB;              // hu-count before bid
    const bool hc = (((long)(bid + 1) * HUB) / TB) == hb;
    const int idx = hc ? (bid - (int)hb) : (int)hb;

    float acc1[16];
    #pragma unroll
    for (int c = 0; c < 16; ++c) acc1[c] = 0.f;

    int base, rows;
    const float* bias;
    unsigned short* table;

    if (hc) {
        base = idx * 64;
        rows = (M - base < 64) ? (M - base) : 64;
        bias = b_h;
        table = Ahc;
        #pragma unroll
        for (int i = 0; i < 4; ++i) {
            int f = i * 256 + t;
            int r = f >> 4, ch = f & 15;
            float4 v = make_float4(0.f, 0.f, 0.f, 0.f);
            if (r < rows) v = *reinterpret_cast<const float4*>(Xc + (size_t)(base + r) * 64 + (ch << 2));
            *reinterpret_cast<float4*>(&s[saddr(r, ch)]) = v;
        }
        __syncthreads();
        __builtin_amdgcn_s_setprio(1);
        for (int b4 = 0; b4 < 4; ++b4)
            s1_batch(s, lane, b4, W_h, wu, acc1);
        __builtin_amdgcn_s_setprio(0);
    } else {
        base = idx * 64;
        rows = (N - base < 64) ? (N - base) : 64;
        bias = b_hlg;
        table = Ahu;
        // software pipeline: xr holds chunk kc while chunk kc is staged;
        // chunk kc+1 prefetched during kc's FMA loop (hides HBM latency).
        float4 xr[4];
        #pragma unroll
        for (int i = 0; i < 4; ++i) {
            int f = i * 256 + t;
            int r = f >> 4, ch = f & 15;
            xr[i] = make_float4(0.f, 0.f, 0.f, 0.f);
            if (r < rows)
                xr[i] = *reinterpret_cast<const float4*>(Xu + (size_t)(base + r) * 256 + (ch << 2));
        }
        for (int kc = 0; kc < 4; ++kc) {
            __syncthreads();           // all waves done reading previous chunk
            #pragma unroll
            for (int i = 0; i < 4; ++i) {
                int f = i * 256 + t;
                int r = f >> 4, ch = f & 15;
                *reinterpret_cast<float4*>(&s[saddr(r, ch)]) = xr[i];
            }
            __syncthreads();
            if (kc + 1 < 4) {
                #pragma unroll
                for (int i = 0; i < 4; ++i) {
                    int f = i * 256 + t;
                    int r = f >> 4, ch = f & 15;
                    if (r < rows)
                        xr[i] = *reinterpret_cast<const float4*>(
                            Xu + (size_t)(base + r) * 256 + (kc + 1) * 64 + (ch << 2));
                }
            }
            const float* Wb = W_hlg + (size_t)kc * 64 * 64;
            __builtin_amdgcn_s_setprio(1);
            for (int b4 = 0; b4 < 4; ++b4)
                s1_batch(s, lane, b4, Wb, wu, acc1);
            __builtin_amdgcn_s_setprio(0);
        }
    }

    // tanh -> bf16 (single plane), write into LDS (s is dead now)
    __syncthreads();
    {
        unsigned short hi[16];
        #pragma unroll
        for (int c = 0; c < 16; ++c)
            hi[c] = bf16r(fast_tanh(acc1[c] + bias[wu * 16 + c]));
        int o = lane * 68 + wu * 16;
        #pragma unroll
        for (int c = 0; c < 16; ++c) hhi[o + c] = hi[c];
    }
    __syncthreads();

    // stage2 MFMA: wave wu owns col-groups g = 4wu..4wu+3; K=64 (2 steps) x {Whi,Wlo}
    const s16x8* Bph = reinterpret_cast<const s16x8*>(Bp);
    const s16x8* Bpl = reinterpret_cast<const s16x8*>(Bp + 16384);
    const int l15 = lane & 15, l4 = lane >> 4;
    for (int rt = 0; rt < 4; ++rt) {
        int arow = (rt * 16 + l15) * 68 + l4 * 8;
        s16x8 a0v = *reinterpret_cast<const s16x8*>(&hhi[arow]);
        s16x8 a1v = *reinterpret_cast<const s16x8*>(&hhi[arow + 32]);
        #pragma unroll
        for (int ct = 0; ct < 4; ++ct) {
            int g = wu * 4 + ct;
            s16x8 bh0 = Bph[(g * 2 + 0) * 64 + lane];
            s16x8 bh1 = Bph[(g * 2 + 1) * 64 + lane];
            s16x8 bl0v = Bpl[(g * 2 + 0) * 64 + lane];
            s16x8 bl1v = Bpl[(g * 2 + 1) * 64 + lane];
            f32x4 acc = {0.f, 0.f, 0.f, 0.f};
            acc = __builtin_amdgcn_mfma_f32_16x16x32_bf16(a0v, bh0, acc, 0, 0, 0);
            acc = __builtin_amdgcn_mfma_f32_16x16x32_bf16(a1v, bh1, acc, 0, 0, 0);
            acc = __builtin_amdgcn_mfma_f32_16x16x32_bf16(a0v, bl0v, acc, 0, 0, 0);
            acc = __builtin_amdgcn_mfma_f32_16x16x32_bf16(a1v, bl1v, acc, 0, 0, 0);
            // fold edge-side biases into the hu table: l0 cols get bl0, r0 cols br0
            float badd = 0.f;
            if (!hc) {
                if (g < 4) badd = bl0[g * 16 + l15];
                else if (g >= 8 && g < 12) badd = br0[(g - 8) * 16 + l15];
            }
            // pair-packed column position: u16 index within 256-u16 row
            int side = g >> 3, which = (g >> 2) & 1;
            int x = (g & 3) * 16 + l15;
            int pos = side * 128 + x * 2 + which;
            #pragma unroll
            for (int r = 0; r < 4; ++r)
                dstage[(l4 * 4 + r) * 264 + pos] = bf16r(acc[r] + badd);
        }
        __syncthreads();
        // coalesced flush: 16 rows x 256 u16; 256 thr x 2 x u16x8
        #pragma unroll
        for (int it = 0; it < 2; ++it) {
            int f = (it * 256 + t) * 8;
            int row = f >> 8, off = f & 255;
            u16x8 v = *reinterpret_cast<const u16x8*>(&dstage[row * 264 + off]);
            int grow = rt * 16 + row;
            if (grow < rows)
                *reinterpret_cast<u16x8*>(&table[(size_t)(base + grow) * 256 + off]) = v;
        }
        __syncthreads();
    }
}

// 16 lanes per edge: contiguous 256B half-row reads, 4 tanh-pairs/lane, 4-level reduce.
// Folds ey*natt into trans and emits int2{outidx,seg} aux for a lean k_final.
__global__ void k_edge(const int* __restrict__ se, const int* __restrict__ inv,
                       const unsigned int* __restrict__ Ahc, const unsigned int* __restrict__ Ahu,
                       const float* __restrict__ ql1b, const float* __restrict__ qr1b,
                       const float* __restrict__ ey, const float* __restrict__ natt,
                       float* __restrict__ trans, float* __restrict__ psum,
                       int2* __restrict__ aux, int E, int N, int ZROW) {
    int tid = blockIdx.x * blockDim.x + threadIdx.x;
    int e = tid >> 4;
    int sl = tid & 15;
    if (e >= E) return;
    const int4* sr = reinterpret_cast<const int4*>(se + (size_t)e * 8);
    int4 ra = sr[0], rb = sr[1];
    int eg = ra.x, vi = ra.y, vj = ra.z, seg = rb.x, e2vi = rb.z, e2vj = rb.w;
    int ii = inv[e2vi]; ii = (ii < 0) ? ZROW : ii;
    int ij = inv[e2vj]; ij = (ij < 0) ? ZROW : ij;
    uint4 a  = *reinterpret_cast<const uint4*>(Ahc + (size_t)ii * 128 + sl * 4);
    uint4 b  = *reinterpret_cast<const uint4*>(Ahu + (size_t)vi * 128 + sl * 4);
    uint4 c  = *reinterpret_cast<const uint4*>(Ahc + (size_t)ij * 128 + 64 + sl * 4);
    uint4 d4 = *reinterpret_cast<const uint4*>(Ahu + (size_t)vj * 128 + 64 + sl * 4);
    float4 q1 = *reinterpret_cast<const float4*>(ql1b + eg * 64 + sl * 4);
    float4 q2 = *reinterpret_cast<const float4*>(qr1b + eg * 64 + sl * 4);
    float acc = 0.f;
    #pragma unroll
    for (int j = 0; j < 4; ++j) {
        unsigned int av = (&a.x)[j], bv = (&b.x)[j];
        unsigned int cv = (&c.x)[j], dv = (&d4.x)[j];
        float l0 = fast_tanh(blo(av) + blo(bv));                 // bl0 folded in Ahu
        float l1 = fast_tanh(bhi(av) + bhi(bv) + (&q1.x)[j]);
        float r0 = fast_tanh(blo(cv) + blo(dv));                 // br0 folded in Ahu
        float r1 = fast_tanh(bhi(cv) + bhi(dv) + (&q2.x)[j]);
        acc = __builtin_fmaf(l0, r0, acc);
        acc = __builtin_fmaf(l1, r1, acc);
    }
    #pragma unroll
    for (int off = 8; off; off >>= 1) acc += __shfl_xor(acc, off);
    if (sl == 0) {
        float ex = __expf(acc);          // |logit| small & inputs fixed: no max pass
        trans[e] = ex * ey[e] * natt[(size_t)eg * N + vi];
        aux[e] = make_int2(eg * N + vj, seg);
        atomicAdd(&psum[seg], ex);
    }
}

__global__ void k_final(const int2* __restrict__ aux, const float* __restrict__ trans,
                        const float* __restrict__ psum, float* __restrict__ out, int E) {
    int e = blockIdx.x * blockDim.x + threadIdx.x;
    if (e >= E) return;
    int2 a = aux[e];
    float t = trans[e] * __builtin_amdgcn_rcpf(psum[a.y]);
    atomicAdd(&out[a.x], t);
}

extern "C" void kernel_launch(void* const* d_in, const int* in_sizes, int n_in,
                              void* d_out, int out_size, void* d_ws, size_t ws_size,
                              hipStream_t stream) {
    const float* natt  = (const float*)d_in[0];
    const float* ey    = (const float*)d_in[1];
    const float* h_unc = (const float*)d_in[2];
    const float* h_con = (const float*)d_in[3];
    const float* qhe   = (const float*)d_in[4];
    const float* qre   = (const float*)d_in[5];
    const float* W_h   = (const float*)d_in[6];
    const float* b_h   = (const float*)d_in[7];
    const float* W_hlg = (const float*)d_in[8];
    const float* b_hlg = (const float*)d_in[9];
    const float* W_rlg = (const float*)d_in[10];
    const float* b_rlg = (const float*)d_in[11];
    const float* Wl0   = (const float*)d_in[12];
    const float* bl0   = (const float*)d_in[13];
    const float* Wr0   = (const float*)d_in[14];
    const float* br0   = (const float*)d_in[15];
    const float* Wl1   = (const float*)d_in[16];
    const float* bl1   = (const float*)d_in[17];
    const float* Wr1   = (const float*)d_in[18];
    const float* br1   = (const float*)d_in[19];
    const int* se      = (const int*)d_in[20];
    const int* new_idx = (const int*)d_in[21];

    const int B     = 32;
    const int N     = in_sizes[0] / B;    // 50000
    const int E     = in_sizes[20] / 8;   // 200000
    const int M_MEM = in_sizes[21];       // 80000
    const int M_ALL = 100000;
    const int NSEG  = 80000;

    char* ws = (char*)d_ws;
    size_t off = 0;
    unsigned short* Ahc = (unsigned short*)(ws + off);  off += (size_t)(M_MEM + 1) * 256 * 2;
    unsigned short* Ahu = (unsigned short*)(ws + off);  off += (size_t)N * 256 * 2;
    int* inv = (int*)(ws + off);            off += (size_t)M_ALL * 4;
    float* trans = (float*)(ws + off);      off += (size_t)E * 4;
    float* psum = (float*)(ws + off);       off += (size_t)NSEG * 4;
    int2* aux = (int2*)(ws + off);          off += (size_t)E * 8;
    float* ql1b = (float*)(ws + off);       off += (size_t)B * 64 * 4;
    float* qr1b = (float*)(ws + off);       off += (size_t)B * 64 * 4;
    unsigned short* Bpack = (unsigned short*)(ws + off); off += (size_t)2 * 16384 * 2;

    hipMemsetAsync(d_out, 0, (size_t)out_size * 4, stream);
    hipMemsetAsync(inv, 0xFF, (size_t)M_ALL * 4, stream);               // -1
    hipMemsetAsync(psum, 0, (size_t)NSEG * 4, stream);
    hipMemsetAsync(Ahc + (size_t)M_MEM * 256, 0, 256 * 2, stream);      // zero sink row

    const int HCB = (M_MEM + 63) / 64;          // 1250
    const int HUB = (N + 63) / 64;              // 782
    const int SCB = (M_MEM + 255) / 256;        // 313

    k_prolog<<<SCB + 16, 256, 0, stream>>>(new_idx, inv, M_MEM,
                                           Wl0, Wl1, Wr0, Wr1, Bpack,
                                           qhe, qre, W_hlg, b_hlg, W_rlg, b_rlg,
                                           bl1, br1, ql1b, qr1b, SCB);
    k_tab<<<HCB + HUB, 256, 0, stream>>>(h_con, h_unc, W_h, b_h, W_hlg, b_hlg,
                                         bl0, br0, Bpack, Ahc, Ahu, M_MEM, N, HUB);
    k_edge<<<((size_t)E * 16 + 255) / 256, 256, 0, stream>>>(se, inv, (const unsigned int*)Ahc,
                                                (const unsigned int*)Ahu, ql1b, qr1b,
                                                ey, natt, trans, psum, aux, E, N, M_MEM);
    k_final<<<(E + 255) / 256, 256, 0, stream>>>(aux, trans, psum, (float*)d_out, E);
}

// Round 18
// 134.106 us; speedup vs baseline: 1.2139x; 1.0165x over previous
//
#include <hip/hip_runtime.h>

// ---------------------------------------------------------------------------
// AttentionFlow: linearized per-node-table formulation.
//   hc   = tanh(hidden_con @ W_h + b_h)                      (80000 x 64)
//   hu   = tanh(hidden_uncon @ W_hlg + b_hlg)                (50000 x 64)
//   Ahc  = hc @ [Wl0 | Wl1_top | Wr0 | Wr1_top]              (80001 x 256) bf16
//   Ahu  = hu @ [Wl0 | Wl1_top | Wr0 | Wr1_top] + [bl0|0|br0|0] (50000 x 256) bf16
// Tables PAIR-PACKED as u32 rows of 128: u32[x] = (l0_x lo16, l1_x hi16),
// u32[64+x] = (r0_x, r1_x). Ahc row M_MEM is all-zero (unmapped-node sink).
// per edge: l0/l1/r0/r1 tanh-dots -> logit -> exp -> segment-sum -> scatter.
//
// Structure = round-17 (136.3us) + stage2 B-fragment HOIST: the 16 s16x8
// B-frags are rt-invariant but were re-loaded (and vmcnt-waited) in each of
// the 4 barrier-serialized rt phases -> 48 redundant L2-latency loads/wave.
// Hoisted to registers (+64 VGPR); launch_bounds relaxed to (256,4) (measured
// occupancy ~3.5 blk/CU, cap non-binding). badd/pos also hoisted.
// r16 lesson: per-lane own-row global X = address divergence; LDS staging IS
// the coalescing device. r13: W stays SMEM (readfirstlane). r12: occupancy
// push thrashed L2. r14: x batched into VGPRs. r15: Bresenham interleave +
// setprio. r17: fused prolog.
// k_edge: 16 lanes/edge (r6/r7 granularity lessons).
// Fragment layouts (verified on-device r5-r8):
//   A: lane holds A[m=lane&15][k=8*(lane>>4)+i]; B: B[k=8*(lane>>4)+i][n=lane&15]
//   D: lane holds D[m=(lane>>4)*4+r][n=lane&15]
// ---------------------------------------------------------------------------

typedef __attribute__((ext_vector_type(8))) short s16x8;
typedef __attribute__((ext_vector_type(4))) float f32x4;
typedef __attribute__((ext_vector_type(8))) unsigned short u16x8;

__device__ __forceinline__ float fast_tanh(float x) {
    float e = __expf(2.0f * x);
    return 1.0f - 2.0f * __builtin_amdgcn_rcpf(e + 1.0f);
}

__device__ __forceinline__ unsigned short bf16r(float f) {   // round-to-nearest-even
    unsigned int u = __float_as_uint(f);
    u = (u + 0x7fffu + ((u >> 16) & 1u)) >> 16;
    return (unsigned short)u;
}
__device__ __forceinline__ float bf16f(unsigned short h) {
    return __uint_as_float(((unsigned int)h) << 16);
}
__device__ __forceinline__ float blo(unsigned int u) {       // low bf16 of pair
    return __uint_as_float(u << 16);
}
__device__ __forceinline__ float bhi(unsigned int u) {       // high bf16 of pair
    return __uint_as_float(u & 0xffff0000u);
}

// swizzled LDS address for fp32 X staging: row stride 64 floats, 16B-chunk XOR
__device__ __forceinline__ int saddr(int row, int chunk) {
    return (row << 6) + ((chunk ^ (row & 7)) << 2);
}

// Fused prolog: blocks [0,SCB) scatter_inv; [SCB,SCB+8) pack; [SCB+8,SCB+16) q.
__global__ void k_prolog(const int* __restrict__ new_idx, int* __restrict__ inv, int M,
                         const float* __restrict__ Wl0, const float* __restrict__ Wl1,
                         const float* __restrict__ Wr0, const float* __restrict__ Wr1,
                         unsigned short* __restrict__ Bp,
                         const float* __restrict__ qhe, const float* __restrict__ qre,
                         const float* __restrict__ W_hlg, const float* __restrict__ b_hlg,
                         const float* __restrict__ W_rlg, const float* __restrict__ b_rlg,
                         const float* __restrict__ bl1, const float* __restrict__ br1,
                         float* __restrict__ ql1b, float* __restrict__ qr1b,
                         int SCB) {
    const int bid = (int)blockIdx.x;
    const int t = threadIdx.x;
    if (bid < SCB) {
        int i = bid * 256 + t;
        if (i < M) inv[new_idx[i]] = i;
    } else if (bid < SCB + 8) {
        // pack concat-W (64 x 256) into MFMA B-fragment order, hi+lo bf16 planes.
        int tid = (bid - SCB) * 256 + t;
        int lane = tid & 63;
        int ks = (tid >> 6) & 1;
        int g = tid >> 7;                       // 0..15 col-group
        int col = g * 16 + (lane & 15);         // 0..255 in concat table
        int kb = ks * 32 + (lane >> 4) * 8;
        const float* W = (col < 64) ? Wl0 : (col < 128) ? Wl1 : (col < 192) ? Wr0 : Wr1;
        int c = col & 63;
        #pragma unroll
        for (int i = 0; i < 8; ++i) {
            float w = W[(kb + i) * 64 + c];
            unsigned short hi = bf16r(w);
            unsigned short lo = bf16r(w - bf16f(hi));
            Bp[(size_t)tid * 8 + i] = hi;
            Bp[16384 + (size_t)tid * 8 + i] = lo;
        }
    } else {
        // q-side precompute: 4 batch-rows per block
        __shared__ float qv_s[4][64];
        int sub = t >> 6, d = t & 63;
        int b = (bid - SCB - 8) * 4 + sub;      // 0..31
        float ah = 0.f, ar = 0.f;
        for (int k = 0; k < 256; ++k) {
            ah += qhe[b * 256 + k] * W_hlg[k * 64 + d];
            ar += qre[b * 256 + k] * W_rlg[k * 64 + d];
        }
        qv_s[sub][d] = fast_tanh(ah + b_hlg[d]) + fast_tanh(ar + b_rlg[d]);
        __syncthreads();
        float a1 = 0.f, a2 = 0.f;
        for (int k = 0; k < 64; ++k) {
            float v = qv_s[sub][k];
            a1 += v * Wl1[(64 + k) * 64 + d];
            a2 += v * Wr1[(64 + k) * 64 + d];
        }
        ql1b[b * 64 + d] = a1 + bl1[d];
        qr1b[b * 64 + d] = a2 + br1[d];
    }
}

// stage1 inner: one batch of 4 k4-groups; x in VGPRs (static idx), W via SMEM
__device__ __forceinline__ void s1_batch(const float* __restrict__ s, int lane, int b4,
                                         const float* __restrict__ Wbase, int wu,
                                         float acc1[16]) {
    f32x4 xrow[4];
    #pragma unroll
    for (int j = 0; j < 4; ++j)
        xrow[j] = *reinterpret_cast<const f32x4*>(&s[saddr(lane, b4 * 4 + j)]);
    #pragma unroll
    for (int k4 = 0; k4 < 4; ++k4) {
        #pragma unroll
        for (int kk = 0; kk < 4; ++kk) {
            float xk = xrow[k4][kk];
            const float* wrow = Wbase + ((b4 * 4 + k4) * 4 + kk) * 64 + wu * 16;  // wave-uniform -> s_load
            #pragma unroll
            for (int c = 0; c < 16; ++c) acc1[c] = __builtin_fmaf(xk, wrow[c], acc1[c]);
        }
    }
}

// fused table builder; hc/hu blocks Bresenham-interleaved over blockIdx
__global__ __launch_bounds__(256, 4) void k_tab(
        const float* __restrict__ Xc, const float* __restrict__ Xu,
        const float* __restrict__ W_h, const float* __restrict__ b_h,
        const float* __restrict__ W_hlg, const float* __restrict__ b_hlg,
        const float* __restrict__ bl0, const float* __restrict__ br0,
        const unsigned short* __restrict__ Bp,
        unsigned short* __restrict__ Ahc, unsigned short* __restrict__ Ahu,
        int M, int N, int HUB) {
    __shared__ float s[64 * 64];                   // X fp32 staging; reused as h bf16 [64][68]
    __shared__ unsigned short dstage[16 * 264];    // D staging (16 rows x 256 + pad)
    unsigned short* hhi = reinterpret_cast<unsigned short*>(s);

    const int t = threadIdx.x;
    const int wu = __builtin_amdgcn_readfirstlane(t >> 6);
    const int lane = t & 63;

    // Bresenham interleave: exactly HUB hu-blocks spread uniformly over TB
    const int bid = (int)blockIdx.x;
    const int TB = (int)gridDim.x;
    const long hb = ((long)bid * HUB) / TB;              // hu-count before bid
    const bool hc = (((long)(bid + 1) * HUB) / TB) == hb;
    const int idx = hc ? (bid - (int)hb) : (int)hb;

    float acc1[16];
    #pragma unroll
    for (int c = 0; c < 16; ++c) acc1[c] = 0.f;

    int base, rows;
    const float* bias;
    unsigned short* table;

    if (hc) {
        base = idx * 64;
        rows = (M - base < 64) ? (M - base) : 64;
        bias = b_h;
        table = Ahc;
        #pragma unroll
        for (int i = 0; i < 4; ++i) {
            int f = i * 256 + t;
            int r = f >> 4, ch = f & 15;
            float4 v = make_float4(0.f, 0.f, 0.f, 0.f);
            if (r < rows) v = *reinterpret_cast<const float4*>(Xc + (size_t)(base + r) * 64 + (ch << 2));
            *reinterpret_cast<float4*>(&s[saddr(r, ch)]) = v;
        }
        __syncthreads();
        __builtin_amdgcn_s_setprio(1);
        for (int b4 = 0; b4 < 4; ++b4)
            s1_batch(s, lane, b4, W_h, wu, acc1);
        __builtin_amdgcn_s_setprio(0);
    } else {
        base = idx * 64;
        rows = (N - base < 64) ? (N - base) : 64;
        bias = b_hlg;
        table = Ahu;
        // software pipeline: xr holds chunk kc while chunk kc is staged;
        // chunk kc+1 prefetched during kc's FMA loop (hides HBM latency).
        float4 xr[4];
        #pragma unroll
        for (int i = 0; i < 4; ++i) {
            int f = i * 256 + t;
            int r = f >> 4, ch = f & 15;
            xr[i] = make_float4(0.f, 0.f, 0.f, 0.f);
            if (r < rows)
                xr[i] = *reinterpret_cast<const float4*>(Xu + (size_t)(base + r) * 256 + (ch << 2));
        }
        for (int kc = 0; kc < 4; ++kc) {
            __syncthreads();           // all waves done reading previous chunk
            #pragma unroll
            for (int i = 0; i < 4; ++i) {
                int f = i * 256 + t;
                int r = f >> 4, ch = f & 15;
                *reinterpret_cast<float4*>(&s[saddr(r, ch)]) = xr[i];
            }
            __syncthreads();
            if (kc + 1 < 4) {
                #pragma unroll
                for (int i = 0; i < 4; ++i) {
                    int f = i * 256 + t;
                    int r = f >> 4, ch = f & 15;
                    if (r < rows)
                        xr[i] = *reinterpret_cast<const float4*>(
                            Xu + (size_t)(base + r) * 256 + (kc + 1) * 64 + (ch << 2));
                }
            }
            const float* Wb = W_hlg + (size_t)kc * 64 * 64;
            __builtin_amdgcn_s_setprio(1);
            for (int b4 = 0; b4 < 4; ++b4)
                s1_batch(s, lane, b4, Wb, wu, acc1);
            __builtin_amdgcn_s_setprio(0);
        }
    }

    // tanh -> bf16 (single plane), write into LDS (s is dead now)
    __syncthreads();
    {
        unsigned short hi[16];
        #pragma unroll
        for (int c = 0; c < 16; ++c)
            hi[c] = bf16r(fast_tanh(acc1[c] + bias[wu * 16 + c]));
        int o = lane * 68 + wu * 16;
        #pragma unroll
        for (int c = 0; c < 16; ++c) hhi[o + c] = hi[c];
    }

    // ---- hoist rt-invariant stage2 operands while the h-write settles:
    // B-frags (16 x s16x8, L2-hot), bias-add, and packed column positions.
    const s16x8* Bph = reinterpret_cast<const s16x8*>(Bp);
    const s16x8* Bpl = reinterpret_cast<const s16x8*>(Bp + 16384);
    const int l15 = lane & 15, l4 = lane >> 4;
    s16x8 rbh0[4], rbh1[4], rbl0[4], rbl1[4];
    float badd[4];
    int posv[4];
    #pragma unroll
    for (int ct = 0; ct < 4; ++ct) {
        int g = wu * 4 + ct;
        rbh0[ct] = Bph[(g * 2 + 0) * 64 + lane];
        rbh1[ct] = Bph[(g * 2 + 1) * 64 + lane];
        rbl0[ct] = Bpl[(g * 2 + 0) * 64 + lane];
        rbl1[ct] = Bpl[(g * 2 + 1) * 64 + lane];
        float ba = 0.f;
        if (!hc) {
            if (g < 4) ba = bl0[g * 16 + l15];
            else if (g >= 8 && g < 12) ba = br0[(g - 8) * 16 + l15];
        }
        badd[ct] = ba;
        int side = g >> 3, which = (g >> 2) & 1;
        int x = (g & 3) * 16 + l15;
        posv[ct] = side * 128 + x * 2 + which;
    }
    __syncthreads();

    // stage2 MFMA: wave wu owns col-groups g = 4wu..4wu+3; K=64 (2 steps) x {Whi,Wlo}
    for (int rt = 0; rt < 4; ++rt) {
        int arow = (rt * 16 + l15) * 68 + l4 * 8;
        s16x8 a0v = *reinterpret_cast<const s16x8*>(&hhi[arow]);
        s16x8 a1v = *reinterpret_cast<const s16x8*>(&hhi[arow + 32]);
        #pragma unroll
        for (int ct = 0; ct < 4; ++ct) {
            f32x4 acc = {0.f, 0.f, 0.f, 0.f};
            acc = __builtin_amdgcn_mfma_f32_16x16x32_bf16(a0v, rbh0[ct], acc, 0, 0, 0);
            acc = __builtin_amdgcn_mfma_f32_16x16x32_bf16(a1v, rbh1[ct], acc, 0, 0, 0);
            acc = __builtin_amdgcn_mfma_f32_16x16x32_bf16(a0v, rbl0[ct], acc, 0, 0, 0);
            acc = __builtin_amdgcn_mfma_f32_16x16x32_bf16(a1v, rbl1[ct], acc, 0, 0, 0);
            #pragma unroll
            for (int r = 0; r < 4; ++r)
                dstage[(l4 * 4 + r) * 264 + posv[ct]] = bf16r(acc[r] + badd[ct]);
        }
        __syncthreads();
        // coalesced flush: 16 rows x 256 u16; 256 thr x 2 x u16x8
        #pragma unroll
        for (int it = 0; it < 2; ++it) {
            int f = (it * 256 + t) * 8;
            int row = f >> 8, off = f & 255;
            u16x8 v = *reinterpret_cast<const u16x8*>(&dstage[row * 264 + off]);
            int grow = rt * 16 + row;
            if (grow < rows)
                *reinterpret_cast<u16x8*>(&table[(size_t)(base + grow) * 256 + off]) = v;
        }
        __syncthreads();
    }
}

// 16 lanes per edge: contiguous 256B half-row reads, 4 tanh-pairs/lane, 4-level reduce.
// Folds ey*natt into trans and emits int2{outidx,seg} aux for a lean k_final.
__global__ void k_edge(const int* __restrict__ se, const int* __restrict__ inv,
                       const unsigned int* __restrict__ Ahc, const unsigned int* __restrict__ Ahu,
                       const float* __restrict__ ql1b, const float* __restrict__ qr1b,
                       const float* __restrict__ ey, const float* __restrict__ natt,
                       float* __restrict__ trans, float* __restrict__ psum,
                       int2* __restrict__ aux, int E, int N, int ZROW) {
    int tid = blockIdx.x * blockDim.x + threadIdx.x;
    int e = tid >> 4;
    int sl = tid & 15;
    if (e >= E) return;
    const int4* sr = reinterpret_cast<const int4*>(se + (size_t)e * 8);
    int4 ra = sr[0], rb = sr[1];
    int eg = ra.x, vi = ra.y, vj = ra.z, seg = rb.x, e2vi = rb.z, e2vj = rb.w;
    int ii = inv[e2vi]; ii = (ii < 0) ? ZROW : ii;
    int ij = inv[e2vj]; ij = (ij < 0) ? ZROW : ij;
    uint4 a  = *reinterpret_cast<const uint4*>(Ahc + (size_t)ii * 128 + sl * 4);
    uint4 b  = *reinterpret_cast<const uint4*>(Ahu + (size_t)vi * 128 + sl * 4);
    uint4 c  = *reinterpret_cast<const uint4*>(Ahc + (size_t)ij * 128 + 64 + sl * 4);
    uint4 d4 = *reinterpret_cast<const uint4*>(Ahu + (size_t)vj * 128 + 64 + sl * 4);
    float4 q1 = *reinterpret_cast<const float4*>(ql1b + eg * 64 + sl * 4);
    float4 q2 = *reinterpret_cast<const float4*>(qr1b + eg * 64 + sl * 4);
    float acc = 0.f;
    #pragma unroll
    for (int j = 0; j < 4; ++j) {
        unsigned int av = (&a.x)[j], bv = (&b.x)[j];
        unsigned int cv = (&c.x)[j], dv = (&d4.x)[j];
        float l0 = fast_tanh(blo(av) + blo(bv));                 // bl0 folded in Ahu
        float l1 = fast_tanh(bhi(av) + bhi(bv) + (&q1.x)[j]);
        float r0 = fast_tanh(blo(cv) + blo(dv));                 // br0 folded in Ahu
        float r1 = fast_tanh(bhi(cv) + bhi(dv) + (&q2.x)[j]);
        acc = __builtin_fmaf(l0, r0, acc);
        acc = __builtin_fmaf(l1, r1, acc);
    }
    #pragma unroll
    for (int off = 8; off; off >>= 1) acc += __shfl_xor(acc, off);
    if (sl == 0) {
        float ex = __expf(acc);          // |logit| small & inputs fixed: no max pass
        trans[e] = ex * ey[e] * natt[(size_t)eg * N + vi];
        aux[e] = make_int2(eg * N + vj, seg);
        atomicAdd(&psum[seg], ex);
    }
}

__global__ void k_final(const int2* __restrict__ aux, const float* __restrict__ trans,
                        const float* __restrict__ psum, float* __restrict__ out, int E) {
    int e = blockIdx.x * blockDim.x + threadIdx.x;
    if (e >= E) return;
    int2 a = aux[e];
    float t = trans[e] * __builtin_amdgcn_rcpf(psum[a.y]);
    atomicAdd(&out[a.x], t);
}

extern "C" void kernel_launch(void* const* d_in, const int* in_sizes, int n_in,
                              void* d_out, int out_size, void* d_ws, size_t ws_size,
                              hipStream_t stream) {
    const float* natt  = (const float*)d_in[0];
    const float* ey    = (const float*)d_in[1];
    const float* h_unc = (const float*)d_in[2];
    const float* h_con = (const float*)d_in[3];
    const float* qhe   = (const float*)d_in[4];
    const float* qre   = (const float*)d_in[5];
    const float* W_h   = (const float*)d_in[6];
    const float* b_h   = (const float*)d_in[7];
    const float* W_hlg = (const float*)d_in[8];
    const float* b_hlg = (const float*)d_in[9];
    const float* W_rlg = (const float*)d_in[10];
    const float* b_rlg = (const float*)d_in[11];
    const float* Wl0   = (const float*)d_in[12];
    const float* bl0   = (const float*)d_in[13];
    const float* Wr0   = (const float*)d_in[14];
    const float* br0   = (const float*)d_in[15];
    const float* Wl1   = (const float*)d_in[16];
    const float* bl1   = (const float*)d_in[17];
    const float* Wr1   = (const float*)d_in[18];
    const float* br1   = (const float*)d_in[19];
    const int* se      = (const int*)d_in[20];
    const int* new_idx = (const int*)d_in[21];

    const int B     = 32;
    const int N     = in_sizes[0] / B;    // 50000
    const int E     = in_sizes[20] / 8;   // 200000
    const int M_MEM = in_sizes[21];       // 80000
    const int M_ALL = 100000;
    const int NSEG  = 80000;

    char* ws = (char*)d_ws;
    size_t off = 0;
    unsigned short* Ahc = (unsigned short*)(ws + off);  off += (size_t)(M_MEM + 1) * 256 * 2;
    unsigned short* Ahu = (unsigned short*)(ws + off);  off += (size_t)N * 256 * 2;
    int* inv = (int*)(ws + off);            off += (size_t)M_ALL * 4;
    float* trans = (float*)(ws + off);      off += (size_t)E * 4;
    float* psum = (float*)(ws + off);       off += (size_t)NSEG * 4;
    int2* aux = (int2*)(ws + off);          off += (size_t)E * 8;
    float* ql1b = (float*)(ws + off);       off += (size_t)B * 64 * 4;
    float* qr1b = (float*)(ws + off);       off += (size_t)B * 64 * 4;
    unsigned short* Bpack = (unsigned short*)(ws + off); off += (size_t)2 * 16384 * 2;

    hipMemsetAsync(d_out, 0, (size_t)out_size * 4, stream);
    hipMemsetAsync(inv, 0xFF, (size_t)M_ALL * 4, stream);               // -1
    hipMemsetAsync(psum, 0, (size_t)NSEG * 4, stream);
    hipMemsetAsync(Ahc + (size_t)M_MEM * 256, 0, 256 * 2, stream);      // zero sink row

    const int HCB = (M_MEM + 63) / 64;          // 1250
    const int HUB = (N + 63) / 64;              // 782
    const int SCB = (M_MEM + 255) / 256;        // 313

    k_prolog<<<SCB + 16, 256, 0, stream>>>(new_idx, inv, M_MEM,
                                           Wl0, Wl1, Wr0, Wr1, Bpack,
                                           qhe, qre, W_hlg, b_hlg, W_rlg, b_rlg,
                                           bl1, br1, ql1b, qr1b, SCB);
    k_tab<<<HCB + HUB, 256, 0, stream>>>(h_con, h_unc, W_h, b_h, W_hlg, b_hlg,
                                         bl0, br0, Bpack, Ahc, Ahu, M_MEM, N, HUB);
    k_edge<<<((size_t)E * 16 + 255) / 256, 256, 0, stream>>>(se, inv, (const unsigned int*)Ahc,
                                                (const unsigned int*)Ahu, ql1b, qr1b,
                                                ey, natt, trans, psum, aux, E, N, M_MEM);
    k_final<<<(E + 255) / 256, 256, 0, stream>>>(aux, trans, psum, (float*)d_out, E);
}